// Round 5
// baseline (591.131 us; speedup 1.0000x reference)
//
#include <hip/hip_runtime.h>
#include <math.h>

#define PSZ 256
#define NPATCH 127
#define L 16129            // 127*127
#define KTOP 4
#define TMAIN 256
#define RPT 2              // rows per thread
#define ROWS_PER_BLOCK (TMAIN * RPT)   // 512
#define NROWBLK 32                     // 32*512 = 16384 >= L
#define NS 16
#define SEGLEN 1009                    // ceil(L/16)
#define MSTRIDE 1012                   // float4-aligned LDS stride
#define ROWPAD 16384
#define TILE_DW (9 * MSTRIDE)          // 9108 dwords B-tile
#define BUFSTRIDE 17                   // dwords per lane-row buffer (16 used + 1 bank pad)

// ---- workspace layout (float elements) ----
static constexpr size_t OFF_CMAX = 0;                          // [2][256][256]
static constexpr size_t OFF_CMIN = OFF_CMAX + 2 * PSZ * PSZ;
static constexpr size_t OFF_REFG = OFF_CMIN + 2 * PSZ * PSZ;
static constexpr size_t OFF_XG   = OFF_REFG + 2 * PSZ * PSZ;
static constexpr size_t OFF_MUI  = OFF_XG   + 2 * PSZ * PSZ;   // [18]
static constexpr size_t OFF_MUR  = OFF_MUI  + 20;
static constexpr size_t OFF_A    = OFF_MUR  + 20;              // [2][L][9] input_norm
static constexpr size_t OFF_B    = OFF_A    + 290324;          // [2][9][L] ref_norm
static constexpr size_t OFF_IDX  = OFF_B    + 290324;          // [2][L][4] int
static constexpr size_t OFF_PV   = OFF_IDX  + 2 * L * 4;       // [2][NS][ROWPAD][4]
static constexpr size_t OFF_PI   = OFF_PV   + (size_t)2 * NS * ROWPAD * 4;
// end ~= 5.1M floats (20.5 MB), well under proven ws (>= 41 MB ran in rounds 2-3)

__device__ __forceinline__ void ins4(float val, int m,
    float& v0, float& v1, float& v2, float& v3,
    int& i0, int& i1, int& i2, int& i3) {
  // strict > everywhere: ties keep the earlier (smaller-m) entry, matching
  // jax.lax.top_k when candidates arrive in ascending m.
  if (val > v3) {
    if (val > v2) {
      v3 = v2; i3 = i2;
      if (val > v1) {
        v2 = v1; i2 = i1;
        if (val > v0) { v1 = v0; i1 = i0; v0 = val; i0 = m; }
        else          { v1 = val; i1 = m; }
      } else { v2 = val; i2 = m; }
    } else { v3 = val; i3 = m; }
  }
}

// k1: per pixel: channel max/min of x, channel mean of ref, copy x -> out[:, :3]
__global__ void k1_pixel(const float* __restrict__ x, const float* __restrict__ ref,
                         float* __restrict__ ws, float* __restrict__ out) {
  int id = blockIdx.x * 256 + threadIdx.x;
  if (id >= 2 * PSZ * PSZ) return;
  int b = id >> 16;
  int pix = id & 0xFFFF;
  const float* xb = x + (size_t)b * 3 * PSZ * PSZ + pix;
  float c0 = xb[0], c1 = xb[PSZ * PSZ], c2 = xb[2 * PSZ * PSZ];
  ws[OFF_CMAX + id] = fmaxf(fmaxf(c0, c1), c2);
  ws[OFF_CMIN + id] = fminf(fminf(c0, c1), c2);
  const float* rb = ref + (size_t)b * 3 * PSZ * PSZ + pix;
  ws[OFF_REFG + id] = (rb[0] + rb[PSZ * PSZ] + rb[2 * PSZ * PSZ]) / 3.0f;
  float* ob = out + (size_t)b * 7 * PSZ * PSZ + pix;
  ob[0] = c0; ob[PSZ * PSZ] = c1; ob[2 * PSZ * PSZ] = c2;
}

// k2: x_gray = 3x3 clipped-window max of cmax - cmin
__global__ void k2_gray(float* __restrict__ ws) {
  int id = blockIdx.x * 256 + threadIdx.x;
  if (id >= 2 * PSZ * PSZ) return;
  int b = id >> 16;
  int pix = id & 0xFFFF;
  int y = pix >> 8, xx = pix & 255;
  const float* cm = ws + OFF_CMAX + ((size_t)b << 16);
  float m = -3.402823466e+38f;
  for (int dy = -1; dy <= 1; ++dy) {
    int yy = y + dy;
    if (yy < 0 || yy > 255) continue;
    for (int dx = -1; dx <= 1; ++dx) {
      int xc = xx + dx;
      if (xc < 0 || xc > 255) continue;
      m = fmaxf(m, cm[yy * PSZ + xc]);
    }
  }
  ws[OFF_XG + id] = m - ws[OFF_CMIN + id];
}

// k4: per-(b,p) mean over L in f64 (deterministic tree reduction)
__global__ void k4_mean(float* __restrict__ ws) {
  __shared__ double sm[256];
  int which = blockIdx.x / 18;  // 0 = input(xg), 1 = ref(rg)
  int bp = blockIdx.x % 18;
  int b = bp / 9, p = bp % 9;
  int di = p / 3, dj = p % 3;
  const float* g = ws + (which ? OFF_REFG : OFF_XG) + ((size_t)b << 16);
  double s = 0.0;
  for (int l = threadIdx.x; l < L; l += 256) {
    int i = l / NPATCH, j = l % NPATCH;
    s += (double)g[(2 * i + di) * PSZ + 2 * j + dj];
  }
  sm[threadIdx.x] = s;
  __syncthreads();
  for (int st = 128; st > 0; st >>= 1) {
    if ((int)threadIdx.x < st) sm[threadIdx.x] += sm[threadIdx.x + st];
    __syncthreads();
  }
  if (threadIdx.x == 0)
    ws[(which ? OFF_MUR : OFF_MUI) + bp] = (float)(sm[0] / (double)L);
}

// k5 (fused with old k3): per l compute patch values + uncentered norms, then
// A[b][l][9] = (ip - muI)/nI ; B[b][9][L] = (rp - muR)/nR
__global__ void k5_norm(float* __restrict__ ws) {
  int id = blockIdx.x * 256 + threadIdx.x;
  if (id >= 2 * L) return;
  int b = id / L, l = id % L;
  int i = l / NPATCH, j = l % NPATCH;
  const float* xg = ws + OFF_XG + ((size_t)b << 16);
  const float* rg = ws + OFF_REFG + ((size_t)b << 16);
  float vi[9], vr[9];
  float si = 0.f, sr = 0.f;
#pragma unroll
  for (int p = 0; p < 9; ++p) {
    int di = p / 3, dj = p % 3;
    vi[p] = xg[(2 * i + di) * PSZ + 2 * j + dj];
    vr[p] = rg[(2 * i + di) * PSZ + 2 * j + dj];
    si += vi[p] * vi[p];
    sr += vr[p] * vr[p];
  }
  float ni = sqrtf(si), nr = sqrtf(sr);
#pragma unroll
  for (int p = 0; p < 9; ++p) {
    float mi = ws[OFF_MUI + b * 9 + p];
    float mr = ws[OFF_MUR + b * 9 + p];
    ws[OFF_A + ((size_t)b * L + l) * 9 + p] = (vi[p] - mi) / ni;
    ws[OFF_B + ((size_t)b * 9 + p) * L + l] = (vr[p] - mr) / nr;
  }
}

// Always-write candidate dump: 1 write2 (DS pipe) + cmp + conditional ptr
// advance. Garbage writes at the unadvanced slot are overwritten / never read.
#define PUSH(sv_, mk_, T) {                                      \
  lds[buf##T + p##T] = (sv_);                                    \
  lds[buf##T + p##T + 1] = __int_as_float(mk_);                  \
  p##T += ((sv_) > tv##T##3) ? 2 : 0;                            \
}

// Drain buffered candidates (ascending-m order preserved) into exact top-4.
#define DRAIN(T) {                                               \
  for (int e = 0; e < p##T; e += 2) {                            \
    float dsv = lds[buf##T + e];                                 \
    int   dmi = __float_as_int(lds[buf##T + e + 1]);             \
    ins4(dsv, dmi, tv##T##0, tv##T##1, tv##T##2, tv##T##3,       \
         ti##T##0, ti##T##1, ti##T##2, ti##T##3);                \
  }                                                              \
  p##T = 0;                                                      \
}

// k6: fused ncc + per-segment top-4 via LDS candidate-dump.
// grid: 2(b) x 32(rowblk) x 16(seg) = 1024 blocks, 256 threads, 2 rows/thread,
// 4 m/iter. Round 4 was VALU-issue-bound (99.6% VALUBusy) with the inline
// sorted-insert running every iteration (wave-any divergence); the dump makes
// per-candidate cost ~4 VALU + 1 DS, with exact ins4 only at rare drains.
// __launch_bounds__(256,2) -> 64-VGPR budget (proven); state ~56 VGPR.
__global__ __launch_bounds__(TMAIN, 2) void k6_topk(float* __restrict__ ws) {
  __shared__ float lds[TILE_DW + TMAIN * 2 * BUFSTRIDE];  // 71,248 B

  int bid = blockIdx.x;
  int seg = bid % NS;
  int rowblk = (bid / NS) % NROWBLK;
  int b = bid / (NS * NROWBLK);
  int m0 = seg * SEGLEN;
  int mend = m0 + SEGLEN;
  if (mend > L) mend = L;
  int mlen = mend - m0;

  const float* Bg = ws + OFF_B + (size_t)b * 9 * L + m0;
  for (int p = 0; p < 9; ++p)
    for (int mm = threadIdx.x; mm < mlen; mm += TMAIN)
      lds[p * MSTRIDE + mm] = Bg[(size_t)p * L + mm];
  __syncthreads();

  int row0 = rowblk * ROWS_PER_BLOCK + threadIdx.x * RPT;
  int r0 = row0 < L - 1 ? row0 : L - 1;
  int r1 = row0 + 1 < L - 1 ? row0 + 1 : L - 1;
  float a0[9], a1[9];
  {
    const float* Ap0 = ws + OFF_A + ((size_t)b * L + r0) * 9;
    const float* Ap1 = ws + OFF_A + ((size_t)b * L + r1) * 9;
#pragma unroll
    for (int p = 0; p < 9; ++p) { a0[p] = Ap0[p]; a1[p] = Ap1[p]; }
  }

  float tv00 = -3.402823466e+38f, tv01 = tv00, tv02 = tv00, tv03 = tv00;
  float tv10 = tv00, tv11 = tv00, tv12 = tv00, tv13 = tv00;
  int ti00 = 0, ti01 = 0, ti02 = 0, ti03 = 0;
  int ti10 = 0, ti11 = 0, ti12 = 0, ti13 = 0;

  // per-lane-row candidate buffers: 8 entries x 2 dwords, stride 17 dwords
  // (lane-to-lane stride 34 dwords -> 2-way bank aliasing, free)
  int buf0 = TILE_DW + (int)threadIdx.x * (2 * BUFSTRIDE);
  int buf1 = buf0 + BUFSTRIDE;
  int p0 = 0, p1 = 0;

  int mlen4 = mlen & ~3;
  for (int mm = 0; mm < mlen4; mm += 4) {
    float s00, s01, s02, s03, s10, s11, s12, s13;
    {
      const float4 bq = *reinterpret_cast<const float4*>(&lds[mm]);
      s00 = a0[0] * bq.x; s01 = a0[0] * bq.y; s02 = a0[0] * bq.z; s03 = a0[0] * bq.w;
      s10 = a1[0] * bq.x; s11 = a1[0] * bq.y; s12 = a1[0] * bq.z; s13 = a1[0] * bq.w;
    }
#pragma unroll
    for (int p = 1; p < 9; ++p) {
      const float4 bq = *reinterpret_cast<const float4*>(&lds[p * MSTRIDE + mm]);
      s00 = fmaf(a0[p], bq.x, s00); s01 = fmaf(a0[p], bq.y, s01);
      s02 = fmaf(a0[p], bq.z, s02); s03 = fmaf(a0[p], bq.w, s03);
      s10 = fmaf(a1[p], bq.x, s10); s11 = fmaf(a1[p], bq.y, s11);
      s12 = fmaf(a1[p], bq.z, s12); s13 = fmaf(a1[p], bq.w, s13);
    }
    int mc = m0 + mm;
    PUSH(s00, mc, 0)     PUSH(s01, mc + 1, 0)
    PUSH(s02, mc + 2, 0) PUSH(s03, mc + 3, 0)
    PUSH(s10, mc, 1)     PUSH(s11, mc + 1, 1)
    PUSH(s12, mc + 2, 1) PUSH(s13, mc + 3, 1)
    // invariant: post-check p <= 8 dwords (4 entries); an iteration adds <= 8
    // dwords, so writes land at dword <= 14 and p <= 16 (buffer holds 16).
    if (__any(p0 > 8 || p1 > 8)) { DRAIN(0) DRAIN(1) }
  }
  // tail (<= 3 candidates; p <= 8 + 6 = 14, safe without trigger)
  for (int mm = mlen4; mm < mlen; ++mm) {
    float bb = lds[mm];
    float sv0 = a0[0] * bb, sv1 = a1[0] * bb;
#pragma unroll
    for (int p = 1; p < 9; ++p) {
      bb = lds[p * MSTRIDE + mm];
      sv0 = fmaf(a0[p], bb, sv0); sv1 = fmaf(a1[p], bb, sv1);
    }
    PUSH(sv0, m0 + mm, 0) PUSH(sv1, m0 + mm, 1)
  }
  DRAIN(0) DRAIN(1)

  int* wsi = (int*)ws;
  if (row0 < L) {
    size_t base = (((size_t)b * NS + seg) * ROWPAD + row0) * 4;
    ws[OFF_PV + base + 0] = tv00; ws[OFF_PV + base + 1] = tv01;
    ws[OFF_PV + base + 2] = tv02; ws[OFF_PV + base + 3] = tv03;
    wsi[OFF_PI + base + 0] = ti00; wsi[OFF_PI + base + 1] = ti01;
    wsi[OFF_PI + base + 2] = ti02; wsi[OFF_PI + base + 3] = ti03;
  }
  if (row0 + 1 < L) {
    size_t base = (((size_t)b * NS + seg) * ROWPAD + row0 + 1) * 4;
    ws[OFF_PV + base + 0] = tv10; ws[OFF_PV + base + 1] = tv11;
    ws[OFF_PV + base + 2] = tv12; ws[OFF_PV + base + 3] = tv13;
    wsi[OFF_PI + base + 0] = ti10; wsi[OFF_PI + base + 1] = ti11;
    wsi[OFF_PI + base + 2] = ti12; wsi[OFF_PI + base + 3] = ti13;
  }
}

// k7: merge per-segment top-4 (segments ascending -> tie-break = lower m first)
__global__ void k7_merge(float* __restrict__ ws) {
  int id = blockIdx.x * 256 + threadIdx.x;
  if (id >= 2 * L) return;
  int b = id / L, row = id % L;
  float v0 = -3.402823466e+38f, v1 = v0, v2 = v0, v3 = v0;
  int i0 = 0, i1 = 0, i2 = 0, i3 = 0;
  const int* wsi_c = (const int*)ws;
  for (int s = 0; s < NS; ++s) {
    size_t base = (((size_t)b * NS + s) * ROWPAD + row) * 4;
    for (int q = 0; q < 4; ++q) {
      float val = ws[OFF_PV + base + q];
      int m = wsi_c[OFF_PI + base + q];
      ins4(val, m, v0, v1, v2, v3, i0, i1, i2, i3);
    }
  }
  int* wsi = (int*)ws;
  size_t ib = OFF_IDX + (size_t)id * 4;
  wsi[ib] = i0; wsi[ib + 1] = i1; wsi[ib + 2] = i2; wsi[ib + 3] = i3;
}

// k8: fold (overlap-add) via per-output-pixel gather; reads ref_gray directly
__global__ void k8_fold(const float* __restrict__ ws, float* __restrict__ out) {
  int id = blockIdx.x * 256 + threadIdx.x;
  if (id >= 2 * KTOP * PSZ * PSZ) return;
  int b = id / (KTOP * PSZ * PSZ);
  int rem = id % (KTOP * PSZ * PSZ);
  int kk = rem >> 16;
  int pix = rem & 0xFFFF;
  int y = pix >> 8, xx = pix & 255;
  const int* wsi = (const int*)ws;
  const float* rg = ws + OFF_REFG + ((size_t)b << 16);
  float acc = 0.f;
  for (int di = 0; di < 3; ++di) {
    int yy = y - di;
    if (yy < 0 || (yy & 1) || (yy >> 1) >= NPATCH) continue;
    int i = yy >> 1;
    for (int dj = 0; dj < 3; ++dj) {
      int xc = xx - dj;
      if (xc < 0 || (xc & 1) || (xc >> 1) >= NPATCH) continue;
      int j = xc >> 1;
      int l = i * NPATCH + j;
      int m = wsi[OFF_IDX + ((size_t)b * L + l) * 4 + kk];
      int mi = m / NPATCH, mj = m % NPATCH;
      acc += rg[(2 * mi + di) * PSZ + 2 * mj + dj];
    }
  }
  out[(((size_t)b * 7 + 3 + kk) * PSZ + y) * PSZ + xx] = acc;
}

extern "C" void kernel_launch(void* const* d_in, const int* in_sizes, int n_in,
                              void* d_out, int out_size, void* d_ws, size_t ws_size,
                              hipStream_t stream) {
  const float* x = (const float*)d_in[0];
  const float* ref = (const float*)d_in[1];
  float* ws = (float*)d_ws;
  float* out = (float*)d_out;

  k1_pixel<<<512, 256, 0, stream>>>(x, ref, ws, out);
  k2_gray<<<512, 256, 0, stream>>>(ws);
  k4_mean<<<36, 256, 0, stream>>>(ws);
  k5_norm<<<(2 * L + 255) / 256, 256, 0, stream>>>(ws);
  k6_topk<<<2 * NROWBLK * NS, TMAIN, 0, stream>>>(ws);
  k7_merge<<<(2 * L + 255) / 256, 256, 0, stream>>>(ws);
  k8_fold<<<(2 * KTOP * PSZ * PSZ + 255) / 256, 256, 0, stream>>>(ws, out);
}

// Round 6
// 239.625 us; speedup vs baseline: 2.4669x; 2.4669x over previous
//
#include <hip/hip_runtime.h>
#include <math.h>
#include <float.h>

#define PSZ 256
#define NPATCH 127
#define L 16129            // 127*127
#define KTOP 4
#define TMAIN 256
#define RPT 2              // rows per thread
#define ROWS_PER_BLOCK (TMAIN * RPT)   // 512
#define NROWBLK 32                     // 32*512 = 16384 >= L
#define NS 16
#define SEGLEN 1009                    // ceil(L/16)
#define MSTRIDE 1012                   // float4-aligned LDS stride
#define ROWPAD 16384
#define GRP 8                          // tournament group size (m's per group)

typedef float f2 __attribute__((ext_vector_type(2)));

// ---- workspace layout (float elements) ----
static constexpr size_t OFF_CMAX = 0;                          // [2][256][256]
static constexpr size_t OFF_CMIN = OFF_CMAX + 2 * PSZ * PSZ;
static constexpr size_t OFF_REFG = OFF_CMIN + 2 * PSZ * PSZ;
static constexpr size_t OFF_XG   = OFF_REFG + 2 * PSZ * PSZ;
static constexpr size_t OFF_MUI  = OFF_XG   + 2 * PSZ * PSZ;   // [18]
static constexpr size_t OFF_MUR  = OFF_MUI  + 20;
static constexpr size_t OFF_A    = OFF_MUR  + 20;              // [2][L][9] input_norm
static constexpr size_t OFF_B    = OFF_A    + 290324;          // [2][9][L] ref_norm (p-major)
static constexpr size_t OFF_BT   = OFF_B    + 290324;          // [2][L][9] ref_norm (m-major)
static constexpr size_t OFF_IDX  = OFF_BT   + 290324;          // [2][L][4] final idx (int)
static constexpr size_t OFF_G4   = OFF_IDX  + 2 * L * 4;       // [2][L][4] winning group bases (int)
static constexpr size_t OFF_PV   = OFF_G4   + 2 * L * 4;       // [2][NS][ROWPAD][4] group-max vals
static constexpr size_t OFF_PI   = OFF_PV   + (size_t)2 * NS * ROWPAD * 4;  // group bases (int)
// end ~= 5.85M floats (23.4 MB) < proven ws (>= 36.9 MB ran in rounds 2-3)

// insert (rm, gb) into sorted-desc (g0..g3, i0..i3); strict > keeps the
// earlier entry on value ties -- candidates arrive in ascending gb.
__device__ __forceinline__ void insg(float rm, int gb,
    float& g0, float& g1, float& g2, float& g3,
    int& i0, int& i1, int& i2, int& i3) {
  bool c0 = rm > g0, c1 = rm > g1, c2 = rm > g2, c3 = rm > g3;
  g3 = c2 ? g2 : (c3 ? rm : g3);  i3 = c2 ? i2 : (c3 ? gb : i3);
  g2 = c1 ? g1 : (c2 ? rm : g2);  i2 = c1 ? i1 : (c2 ? gb : i2);
  g1 = c0 ? g0 : (c1 ? rm : g1);  i1 = c0 ? i0 : (c1 ? gb : i1);
  g0 = c0 ? rm : g0;              i0 = c0 ? gb : i0;
}

// composite-order insert: (v desc, m asc). Order-independent and
// duplicate-safe (identical (v,m) re-inserted is a no-op).
__device__ __forceinline__ void ins4c(float v, int m,
    float& v0, float& v1, float& v2, float& v3,
    int& x0, int& x1, int& x2, int& x3) {
  bool c0 = (v > v0) || (v == v0 && m < x0);
  bool c1 = (v > v1) || (v == v1 && m < x1);
  bool c2 = (v > v2) || (v == v2 && m < x2);
  bool c3 = (v > v3) || (v == v3 && m < x3);
  v3 = c2 ? v2 : (c3 ? v : v3);  x3 = c2 ? x2 : (c3 ? m : x3);
  v2 = c1 ? v1 : (c2 ? v : v2);  x2 = c1 ? x1 : (c2 ? m : x2);
  v1 = c0 ? v0 : (c1 ? v : v1);  x1 = c0 ? x0 : (c1 ? m : x1);
  v0 = c0 ? v : v0;              x0 = c0 ? m : x0;
}

// k1: per pixel: channel max/min of x, channel mean of ref, copy x -> out[:, :3]
__global__ void k1_pixel(const float* __restrict__ x, const float* __restrict__ ref,
                         float* __restrict__ ws, float* __restrict__ out) {
  int id = blockIdx.x * 256 + threadIdx.x;
  if (id >= 2 * PSZ * PSZ) return;
  int b = id >> 16;
  int pix = id & 0xFFFF;
  const float* xb = x + (size_t)b * 3 * PSZ * PSZ + pix;
  float c0 = xb[0], c1 = xb[PSZ * PSZ], c2 = xb[2 * PSZ * PSZ];
  ws[OFF_CMAX + id] = fmaxf(fmaxf(c0, c1), c2);
  ws[OFF_CMIN + id] = fminf(fminf(c0, c1), c2);
  const float* rb = ref + (size_t)b * 3 * PSZ * PSZ + pix;
  ws[OFF_REFG + id] = (rb[0] + rb[PSZ * PSZ] + rb[2 * PSZ * PSZ]) / 3.0f;
  float* ob = out + (size_t)b * 7 * PSZ * PSZ + pix;
  ob[0] = c0; ob[PSZ * PSZ] = c1; ob[2 * PSZ * PSZ] = c2;
}

// k2: x_gray = 3x3 clipped-window max of cmax - cmin
__global__ void k2_gray(float* __restrict__ ws) {
  int id = blockIdx.x * 256 + threadIdx.x;
  if (id >= 2 * PSZ * PSZ) return;
  int b = id >> 16;
  int pix = id & 0xFFFF;
  int y = pix >> 8, xx = pix & 255;
  const float* cm = ws + OFF_CMAX + ((size_t)b << 16);
  float m = -3.402823466e+38f;
  for (int dy = -1; dy <= 1; ++dy) {
    int yy = y + dy;
    if (yy < 0 || yy > 255) continue;
    for (int dx = -1; dx <= 1; ++dx) {
      int xc = xx + dx;
      if (xc < 0 || xc > 255) continue;
      m = fmaxf(m, cm[yy * PSZ + xc]);
    }
  }
  ws[OFF_XG + id] = m - ws[OFF_CMIN + id];
}

// k4: per-(b,p) mean over L in f64 (deterministic tree reduction)
__global__ void k4_mean(float* __restrict__ ws) {
  __shared__ double sm[256];
  int which = blockIdx.x / 18;  // 0 = input(xg), 1 = ref(rg)
  int bp = blockIdx.x % 18;
  int b = bp / 9, p = bp % 9;
  int di = p / 3, dj = p % 3;
  const float* g = ws + (which ? OFF_REFG : OFF_XG) + ((size_t)b << 16);
  double s = 0.0;
  for (int l = threadIdx.x; l < L; l += 256) {
    int i = l / NPATCH, j = l % NPATCH;
    s += (double)g[(2 * i + di) * PSZ + 2 * j + dj];
  }
  sm[threadIdx.x] = s;
  __syncthreads();
  for (int st = 128; st > 0; st >>= 1) {
    if ((int)threadIdx.x < st) sm[threadIdx.x] += sm[threadIdx.x + st];
    __syncthreads();
  }
  if (threadIdx.x == 0)
    ws[(which ? OFF_MUR : OFF_MUI) + bp] = (float)(sm[0] / (double)L);
}

// k5: per l compute patch values + uncentered norms, then
// A[b][l][9] = (ip - muI)/nI ; B[b][9][L] and BT[b][l][9] = (rp - muR)/nR
__global__ void k5_norm(float* __restrict__ ws) {
  int id = blockIdx.x * 256 + threadIdx.x;
  if (id >= 2 * L) return;
  int b = id / L, l = id % L;
  int i = l / NPATCH, j = l % NPATCH;
  const float* xg = ws + OFF_XG + ((size_t)b << 16);
  const float* rg = ws + OFF_REFG + ((size_t)b << 16);
  float vi[9], vr[9];
  float si = 0.f, sr = 0.f;
#pragma unroll
  for (int p = 0; p < 9; ++p) {
    int di = p / 3, dj = p % 3;
    vi[p] = xg[(2 * i + di) * PSZ + 2 * j + dj];
    vr[p] = rg[(2 * i + di) * PSZ + 2 * j + dj];
    si += vi[p] * vi[p];
    sr += vr[p] * vr[p];
  }
  float ni = sqrtf(si), nr = sqrtf(sr);
#pragma unroll
  for (int p = 0; p < 9; ++p) {
    float mi = ws[OFF_MUI + b * 9 + p];
    float mr = ws[OFF_MUR + b * 9 + p];
    float bn = (vr[p] - mr) / nr;
    ws[OFF_A + ((size_t)b * L + l) * 9 + p] = (vi[p] - mi) / ni;
    ws[OFF_B + ((size_t)b * 9 + p) * L + l] = bn;
    ws[OFF_BT + ((size_t)b * L + l) * 9 + p] = bn;
  }
}

// k6: fused ncc + per-(row,segment) top-4 GROUP-MAX tournament (groups of 8 m).
// Superset property: the row's top-4 elements lie in the top-4 groups by
// (group-max desc, base asc) -- exact recovery happens in k7a/k7b.
// grid: 2(b) x 32(rowblk) x 16(seg) = 1024 blocks, 256 threads, 2 rows/thread,
// 8 m/iter. Per iter per row: 36 f2-FMA + 4 max + one 19-op insert (vs round
// 4's per-candidate sorted inserts, ~6x the VALU per m).
__global__ __launch_bounds__(TMAIN, 2) void k6_topk(float* __restrict__ ws) {
  __shared__ float lds[9 * MSTRIDE];  // 36432 B

  int bid = blockIdx.x;
  int seg = bid % NS;
  int rowblk = (bid / NS) % NROWBLK;
  int b = bid / (NS * NROWBLK);
  int m0 = seg * SEGLEN;
  int mend = m0 + SEGLEN;
  if (mend > L) mend = L;
  int mlen = mend - m0;

  const float* Bg = ws + OFF_B + (size_t)b * 9 * L + m0;
  for (int p = 0; p < 9; ++p)
    for (int mm = threadIdx.x; mm < mlen; mm += TMAIN)
      lds[p * MSTRIDE + mm] = Bg[(size_t)p * L + mm];
  __syncthreads();

  int row0 = rowblk * ROWS_PER_BLOCK + threadIdx.x * RPT;
  int r0 = row0 < L - 1 ? row0 : L - 1;
  int r1 = row0 + 1 < L - 1 ? row0 + 1 : L - 1;
  float a0[9], a1[9];
  {
    const float* Ap0 = ws + OFF_A + ((size_t)b * L + r0) * 9;
    const float* Ap1 = ws + OFF_A + ((size_t)b * L + r1) * 9;
#pragma unroll
    for (int p = 0; p < 9; ++p) { a0[p] = Ap0[p]; a1[p] = Ap1[p]; }
  }

  float g00 = -FLT_MAX, g01 = g00, g02 = g00, g03 = g00;
  float g10 = g00, g11 = g00, g12 = g00, g13 = g00;
  int i00 = 0, i01 = 0, i02 = 0, i03 = 0;
  int i10 = 0, i11 = 0, i12 = 0, i13 = 0;

  int ngrp = mlen >> 3;  // full groups of 8
  for (int g = 0; g < ngrp; ++g) {
    int mm = g << 3;
    f2 s0a, s0b, s0c, s0d, s1a, s1b, s1c, s1d;
#pragma unroll
    for (int p = 0; p < 9; ++p) {
      const float* base = &lds[p * MSTRIDE + mm];
      f2 b0 = *(const f2*)(base + 0);
      f2 b1 = *(const f2*)(base + 2);
      f2 b2 = *(const f2*)(base + 4);
      f2 b3 = *(const f2*)(base + 6);
      f2 va = {a0[p], a0[p]};
      f2 vb = {a1[p], a1[p]};
      if (p == 0) {
        s0a = va * b0; s0b = va * b1; s0c = va * b2; s0d = va * b3;
        s1a = vb * b0; s1b = vb * b1; s1c = vb * b2; s1d = vb * b3;
      } else {
        s0a = __builtin_elementwise_fma(va, b0, s0a);
        s0b = __builtin_elementwise_fma(va, b1, s0b);
        s0c = __builtin_elementwise_fma(va, b2, s0c);
        s0d = __builtin_elementwise_fma(va, b3, s0d);
        s1a = __builtin_elementwise_fma(vb, b0, s1a);
        s1b = __builtin_elementwise_fma(vb, b1, s1b);
        s1c = __builtin_elementwise_fma(vb, b2, s1c);
        s1d = __builtin_elementwise_fma(vb, b3, s1d);
      }
    }
    f2 rv0 = __builtin_elementwise_max(__builtin_elementwise_max(s0a, s0b),
                                       __builtin_elementwise_max(s0c, s0d));
    f2 rv1 = __builtin_elementwise_max(__builtin_elementwise_max(s1a, s1b),
                                       __builtin_elementwise_max(s1c, s1d));
    float rm0 = fmaxf(rv0.x, rv0.y);
    float rm1 = fmaxf(rv1.x, rv1.y);
    int gb = m0 + mm;
    insg(rm0, gb, g00, g01, g02, g03, i00, i01, i02, i03);
    insg(rm1, gb, g10, g11, g12, g13, i10, i11, i12, i13);
  }
  // tail (< 8 m): one partial group; recovery clips its scan to L.
  int tb = ngrp << 3;
  if (tb < mlen) {
    float rt0 = -FLT_MAX, rt1 = -FLT_MAX;
    for (int mm = tb; mm < mlen; ++mm) {
      float bb = lds[mm];
      float sv0 = a0[0] * bb, sv1 = a1[0] * bb;
#pragma unroll
      for (int p = 1; p < 9; ++p) {
        bb = lds[p * MSTRIDE + mm];
        sv0 = fmaf(a0[p], bb, sv0); sv1 = fmaf(a1[p], bb, sv1);
      }
      rt0 = fmaxf(rt0, sv0); rt1 = fmaxf(rt1, sv1);
    }
    insg(rt0, m0 + tb, g00, g01, g02, g03, i00, i01, i02, i03);
    insg(rt1, m0 + tb, g10, g11, g12, g13, i10, i11, i12, i13);
  }

  int* wsi = (int*)ws;
  if (row0 < L) {
    size_t base = (((size_t)b * NS + seg) * ROWPAD + row0) * 4;
    ws[OFF_PV + base + 0] = g00; ws[OFF_PV + base + 1] = g01;
    ws[OFF_PV + base + 2] = g02; ws[OFF_PV + base + 3] = g03;
    wsi[OFF_PI + base + 0] = i00; wsi[OFF_PI + base + 1] = i01;
    wsi[OFF_PI + base + 2] = i02; wsi[OFF_PI + base + 3] = i03;
  }
  if (row0 + 1 < L) {
    size_t base = (((size_t)b * NS + seg) * ROWPAD + row0 + 1) * 4;
    ws[OFF_PV + base + 0] = g10; ws[OFF_PV + base + 1] = g11;
    ws[OFF_PV + base + 2] = g12; ws[OFF_PV + base + 3] = g13;
    wsi[OFF_PI + base + 0] = i10; wsi[OFF_PI + base + 1] = i11;
    wsi[OFF_PI + base + 2] = i12; wsi[OFF_PI + base + 3] = i13;
  }
}

// k7a: per row merge 16 segs x 4 (group-max, base) -> top-4 groups by
// (max desc, base asc); store the 4 winning bases.
__global__ void k7a_groups(float* __restrict__ ws) {
  int id = blockIdx.x * 256 + threadIdx.x;
  if (id >= 2 * L) return;
  int b = id / L, row = id % L;
  float v0 = -FLT_MAX, v1 = v0, v2 = v0, v3 = v0;
  int x0 = 0x7FFFFFFF, x1 = x0, x2 = x0, x3 = x0;
  const int* wsi_c = (const int*)ws;
  for (int s = 0; s < NS; ++s) {
    size_t base = (((size_t)b * NS + s) * ROWPAD + row) * 4;
#pragma unroll
    for (int q = 0; q < 4; ++q) {
      float val = ws[OFF_PV + base + q];
      int gb = wsi_c[OFF_PI + base + q];
      ins4c(val, gb, v0, v1, v2, v3, x0, x1, x2, x3);
    }
  }
  int* wsi = (int*)ws;
  size_t gb4 = OFF_G4 + (size_t)id * 4;
  wsi[gb4] = x0; wsi[gb4 + 1] = x1; wsi[gb4 + 2] = x2; wsi[gb4 + 3] = x3;
}

// k7b: exact recovery -- rescan the 4 winning groups (<= 32 m's) with the
// identical fmaf chain, exact composite top-4 -> IDX.
__global__ void k7b_recover(float* __restrict__ ws) {
  int id = blockIdx.x * 256 + threadIdx.x;
  if (id >= 2 * L) return;
  int b = id / L, row = id % L;
  float a[9];
  const float* Ap = ws + OFF_A + ((size_t)b * L + row) * 9;
#pragma unroll
  for (int p = 0; p < 9; ++p) a[p] = Ap[p];
  const int* wsi_c = (const int*)ws;
  float v0 = -FLT_MAX, v1 = v0, v2 = v0, v3 = v0;
  int x0 = 0x7FFFFFFF, x1 = x0, x2 = x0, x3 = x0;
#pragma unroll
  for (int slot = 0; slot < 4; ++slot) {
    int gb = wsi_c[OFF_G4 + (size_t)id * 4 + slot];
    int ge = gb + GRP; if (ge > L) ge = L;
    for (int mm = gb; mm < ge; ++mm) {
      const float* bt = ws + OFF_BT + ((size_t)b * L + mm) * 9;
      float s = a[0] * bt[0];
#pragma unroll
      for (int p = 1; p < 9; ++p) s = fmaf(a[p], bt[p], s);
      ins4c(s, mm, v0, v1, v2, v3, x0, x1, x2, x3);
    }
  }
  int* wsi = (int*)ws;
  size_t ib = OFF_IDX + (size_t)id * 4;
  wsi[ib] = x0; wsi[ib + 1] = x1; wsi[ib + 2] = x2; wsi[ib + 3] = x3;
}

// k8: fold (overlap-add) via per-output-pixel gather; reads ref_gray directly
__global__ void k8_fold(const float* __restrict__ ws, float* __restrict__ out) {
  int id = blockIdx.x * 256 + threadIdx.x;
  if (id >= 2 * KTOP * PSZ * PSZ) return;
  int b = id / (KTOP * PSZ * PSZ);
  int rem = id % (KTOP * PSZ * PSZ);
  int kk = rem >> 16;
  int pix = rem & 0xFFFF;
  int y = pix >> 8, xx = pix & 255;
  const int* wsi = (const int*)ws;
  const float* rg = ws + OFF_REFG + ((size_t)b << 16);
  float acc = 0.f;
  for (int di = 0; di < 3; ++di) {
    int yy = y - di;
    if (yy < 0 || (yy & 1) || (yy >> 1) >= NPATCH) continue;
    int i = yy >> 1;
    for (int dj = 0; dj < 3; ++dj) {
      int xc = xx - dj;
      if (xc < 0 || (xc & 1) || (xc >> 1) >= NPATCH) continue;
      int j = xc >> 1;
      int l = i * NPATCH + j;
      int m = wsi[OFF_IDX + ((size_t)b * L + l) * 4 + kk];
      int mi = m / NPATCH, mj = m % NPATCH;
      acc += rg[(2 * mi + di) * PSZ + 2 * mj + dj];
    }
  }
  out[(((size_t)b * 7 + 3 + kk) * PSZ + y) * PSZ + xx] = acc;
}

extern "C" void kernel_launch(void* const* d_in, const int* in_sizes, int n_in,
                              void* d_out, int out_size, void* d_ws, size_t ws_size,
                              hipStream_t stream) {
  const float* x = (const float*)d_in[0];
  const float* ref = (const float*)d_in[1];
  float* ws = (float*)d_ws;
  float* out = (float*)d_out;

  k1_pixel<<<512, 256, 0, stream>>>(x, ref, ws, out);
  k2_gray<<<512, 256, 0, stream>>>(ws);
  k4_mean<<<36, 256, 0, stream>>>(ws);
  k5_norm<<<(2 * L + 255) / 256, 256, 0, stream>>>(ws);
  k6_topk<<<2 * NROWBLK * NS, TMAIN, 0, stream>>>(ws);
  k7a_groups<<<(2 * L + 255) / 256, 256, 0, stream>>>(ws);
  k7b_recover<<<(2 * L + 255) / 256, 256, 0, stream>>>(ws);
  k8_fold<<<(2 * KTOP * PSZ * PSZ + 255) / 256, 256, 0, stream>>>(ws, out);
}